// Round 1
// baseline (5582.016 us; speedup 1.0000x reference)
//
#include <hip/hip_runtime.h>
#include <cstdint>

// Problem constants (from reference): N=100000 nodes, E=1.6M edges, D=32, 5D=160, ATTR=33
constexpr int D      = 32;
constexpr int FD     = 160;   // 5*D
constexpr int ATTRD  = 33;
constexpr int TILE_E = 32;    // edges per block
constexpr int BLOCK  = 320;   // 5 waves; thread = (eg in [0,8)) x (cg in [0,40))
constexpr int NCG    = 40;    // 160/4 column groups (rn=4)
constexpr int TSTR   = 44;    // sTt row stride in floats: 176B rows -> 16B aligned, conflict-free b128 reads

__device__ __forceinline__ float fast_tanh(float x) {
    // tanh(x) = 1 - 2/(e^{2x}+1); exp overflow -> inf -> rcp=0 -> +1; underflow -> 0 -> -1. No NaN.
    float e = __expf(2.0f * x);
    return 1.0f - 2.0f * __builtin_amdgcn_rcpf(e + 1.0f);
}

__global__ __launch_bounds__(BLOCK)
void prop_fused(const float* __restrict__ xn,
                const float* __restrict__ xe_attr,
                const float* __restrict__ W1,
                const float* __restrict__ b1,
                const float* __restrict__ Wd1,
                const int*   __restrict__ esrc,
                const int*   __restrict__ edst,
                float* __restrict__ out,
                int E)
{
    __shared__ __align__(16) float s_wd[32 * FD];      // 20480 B : Wd1 K-chunk [32][160]
    __shared__ __align__(16) float sTt[FD * TSTR];     // 28160 B : A-matrix transposed [k][e] (+pad)
    __shared__ __align__(16) float s_un[2560];         // 10240 B : union: {attr(1056)+w1(1056)} | {red_s(1280)+red_q(1280)}
    __shared__ float sW[TILE_E * D];                   // 4096  B : silu(fc1) tile
    __shared__ float s_b1[D];
    __shared__ float s_mean[TILE_E], s_scale[TILE_E];
    __shared__ int   s_src[TILE_E], s_dst[TILE_E];
    // total ~63.6 KB -> 2 blocks/CU

    float* s_attr = s_un;                    // [32][33]
    float* s_w1   = s_un + TILE_E * ATTRD;   // [33][32]
    float* red_s  = s_un;                    // [32][40]
    float* red_q  = s_un + TILE_E * NCG;     // [32][40]

    const int tid = threadIdx.x;
    const int cg  = tid % NCG;              // column group: cols 4cg..4cg+3
    const int eg  = tid / NCG;              // edge group:   edges 4eg..4eg+3
    const long e0 = (long)blockIdx.x * TILE_E;
    const int nvalid = min(TILE_E, (int)((long)E - e0));

    // ---------------- Phase A: stage attr tile, W1, b1, indices ----------------
    for (int f = tid; f < TILE_E * ATTRD; f += BLOCK) {
        int e = f / ATTRD;
        s_attr[f] = (e < nvalid) ? xe_attr[e0 * ATTRD + f] : 0.0f;
    }
    for (int f = tid; f < ATTRD * D; f += BLOCK) s_w1[f] = W1[f];
    if (tid < D) s_b1[tid] = b1[tid];
    if (tid < TILE_E) {
        s_src[tid] = (tid < nvalid) ? esrc[e0 + tid] : 0;
        s_dst[tid] = (tid < nvalid) ? edst[e0 + tid] : 0;
    }
    __syncthreads();

    // ---------------- Phase A2: W tile = silu(attr @ W1 + b1) ----------------
    for (int p = tid; p < TILE_E * D; p += BLOCK) {
        int e = p >> 5, j = p & 31;
        float acc = s_b1[j];
        #pragma unroll
        for (int a = 0; a < ATTRD; ++a)
            acc = fmaf(s_attr[e * ATTRD + a], s_w1[a * D + j], acc);
        float sg = __builtin_amdgcn_rcpf(1.0f + __expf(-acc));
        sW[p] = acc * sg;   // silu
    }
    __syncthreads();

    // ---------------- Phase B: gathers + dxe + tanh -> sTt[k][e] ----------------
    for (int p = tid; p < TILE_E * D; p += BLOCK) {
        int e = p >> 5, c = p & 31;
        float w  = sW[p];
        float xs = xn[(long)s_src[e] * D + c];
        float xd = xn[(long)s_dst[e] * D + c];
        float g = w * (xs - xd);
        float a = w * (xs + xd) * 0.5f;
        sTt[(0 * D + c) * TSTR + e] = fast_tanh(g);
        sTt[(1 * D + c) * TSTR + e] = fast_tanh(a);
        sTt[(2 * D + c) * TSTR + e] = fast_tanh(g * a);
        sTt[(3 * D + c) * TSTR + e] = fast_tanh(g * g);
        sTt[(4 * D + c) * TSTR + e] = fast_tanh(a * a);
    }
    __syncthreads();

    float acc[4][4];

    // GEMM: acc[e in 4eg..][j in 4cg..] = sum_k sTt[k][e] * Wd1[k][j], K-chunked Wd1 staging
    auto do_matmul = [&]() {
        #pragma unroll
        for (int i = 0; i < 4; ++i)
            #pragma unroll
            for (int jj = 0; jj < 4; ++jj) acc[i][jj] = 0.0f;
        for (int kb = 0; kb < FD; kb += 32) {
            for (int f = tid; f < (32 * FD) / 4; f += BLOCK)
                reinterpret_cast<float4*>(s_wd)[f] =
                    reinterpret_cast<const float4*>(Wd1 + (size_t)kb * FD)[f];
            __syncthreads();
            #pragma unroll 8
            for (int k = 0; k < 32; ++k) {
                const float4 w4 = *reinterpret_cast<const float4*>(&s_wd[k * FD + 4 * cg]);
                const float4 t4 = *reinterpret_cast<const float4*>(&sTt[(kb + k) * TSTR + 4 * eg]);
                const float tv[4] = {t4.x, t4.y, t4.z, t4.w};
                const float wv[4] = {w4.x, w4.y, w4.z, w4.w};
                #pragma unroll
                for (int i = 0; i < 4; ++i)
                    #pragma unroll
                    for (int jj = 0; jj < 4; ++jj)
                        acc[i][jj] = fmaf(tv[i], wv[jj], acc[i][jj]);
            }
            __syncthreads();
        }
    };

    // ---------------- Matmul 1 ----------------
    do_matmul();

    // ---------------- tv_norm stats (reduce over 160 cols per edge) ----------------
    #pragma unroll
    for (int i = 0; i < 4; ++i) {
        float s = acc[i][0] + acc[i][1] + acc[i][2] + acc[i][3];
        float q = acc[i][0] * acc[i][0] + acc[i][1] * acc[i][1]
                + acc[i][2] * acc[i][2] + acc[i][3] * acc[i][3];
        red_s[(4 * eg + i) * NCG + cg] = s;
        red_q[(4 * eg + i) * NCG + cg] = q;
    }
    __syncthreads();
    if (tid < TILE_E) {
        float s = 0.0f, q = 0.0f;
        for (int c2 = 0; c2 < NCG; ++c2) {
            s += red_s[tid * NCG + c2];
            q += red_q[tid * NCG + c2];
        }
        float mean = s * (1.0f / FD);
        float var  = q - (float)FD * mean * mean;  // sum((x-mean)^2)
        s_mean[tid]  = mean;
        s_scale[tid] = __builtin_amdgcn_rsqf(var + 1e-3f);
    }
    __syncthreads();

    // ---------------- tanh(tv_norm(x)) back into sTt[j][e] ----------------
    #pragma unroll
    for (int jj = 0; jj < 4; ++jj) {
        float4 v; float* vv = reinterpret_cast<float*>(&v);
        #pragma unroll
        for (int i = 0; i < 4; ++i) {
            int e = 4 * eg + i;
            vv[i] = fast_tanh((acc[i][jj] - s_mean[e]) * s_scale[e]);
        }
        *reinterpret_cast<float4*>(&sTt[(4 * cg + jj) * TSTR + 4 * eg]) = v;
    }
    __syncthreads();

    // ---------------- Matmul 2 ----------------
    do_matmul();

    // ---------------- msg = tile(W,5) * tanh(x2) into sTt[j][e] ----------------
    #pragma unroll
    for (int jj = 0; jj < 4; ++jj) {
        float4 v; float* vv = reinterpret_cast<float*>(&v);
        #pragma unroll
        for (int i = 0; i < 4; ++i) {
            int e = 4 * eg + i;
            int j = 4 * cg + jj;
            int c = j & 31;
            vv[i] = fast_tanh(acc[i][jj]) * sW[e * D + c];
        }
        *reinterpret_cast<float4*>(&sTt[(4 * cg + jj) * TSTR + 4 * eg]) = v;
    }
    __syncthreads();

    // ---------------- per-edge chunk reduce + scatter atomics ----------------
    // out[dst] += m0 + 0.5*(m1+m2+m3+m4); out[src] += -m0 + 0.5*(m1+m2+m3+m4)
    for (int p = tid; p < TILE_E * D; p += BLOCK) {
        int e = p >> 5, c = p & 31;
        if (e >= nvalid) continue;
        float B = sTt[c * TSTR + e];
        float A = sTt[(D + c) * TSTR + e] + sTt[(2 * D + c) * TSTR + e]
                + sTt[(3 * D + c) * TSTR + e] + sTt[(4 * D + c) * TSTR + e];
        float dv = B + 0.5f * A;
        float sv = 0.5f * A - B;
        atomicAdd(out + (long)s_dst[e] * D + c, dv);
        atomicAdd(out + (long)s_src[e] * D + c, sv);
    }
}

extern "C" void kernel_launch(void* const* d_in, const int* in_sizes, int n_in,
                              void* d_out, int out_size, void* d_ws, size_t ws_size,
                              hipStream_t stream)
{
    const float* xn   = (const float*)d_in[0];
    const float* attr = (const float*)d_in[1];
    const float* W1   = (const float*)d_in[2];
    const float* b1   = (const float*)d_in[3];
    const float* Wd1  = (const float*)d_in[4];
    const int*   esrc = (const int*)d_in[5];
    const int*   edst = (const int*)d_in[6];
    float* out = (float*)d_out;
    const int E = in_sizes[5];

    hipMemsetAsync(d_out, 0, (size_t)out_size * sizeof(float), stream);
    const int grid = (E + TILE_E - 1) / TILE_E;
    prop_fused<<<grid, BLOCK, 0, stream>>>(xn, attr, W1, b1, Wd1, esrc, edst, out, E);
}

// Round 2
// 1024.418 us; speedup vs baseline: 5.4490x; 5.4490x over previous
//
#include <hip/hip_runtime.h>
#include <hip/hip_bf16.h>
#include <cstdint>

// N=100000 nodes, E=1.6M edges (divisible by 32), D=32, 5D=160, ATTR=33
constexpr int D      = 32;
constexpr int FD     = 160;
constexpr int ATTRD  = 33;
constexpr int TILE_E = 32;
constexpr int BLOCK  = 256;   // 4 waves: wave w -> mtile=w>>1, parity=w&1
constexpr int ASTR   = 168;   // sA row stride (bf16): 336 B = 21*16B -> aligned b128, 2-way banks (free)
constexpr int NKS    = 5;     // K-steps of 32 (K=160)

typedef __attribute__((ext_vector_type(8))) short short8;  // 8 bf16 = 4 VGPRs (MFMA A/B frag)
typedef __attribute__((ext_vector_type(4))) float f32x4;   // MFMA C/D frag

__device__ __forceinline__ float fast_tanh(float x) {
    float e = __expf(2.0f * x);
    return 1.0f - 2.0f * __builtin_amdgcn_rcpf(e + 1.0f);
}
__device__ __forceinline__ unsigned short bf16b(float x) {
    __hip_bfloat16 h = __float2bfloat16(x);   // RNE
    return *reinterpret_cast<unsigned short*>(&h);
}

// Pack Wd1 (fp32 [k][n], 160x160) into bf16 B-fragment lane order in ws:
// chunk (nt,ks) is 64 lanes x 8 bf16; lane L holds B[ks*32 + (L>>4)*8 + j][nt*16 + (L&15)]
__global__ void prep_wd1(const float* __restrict__ Wd1, unsigned short* __restrict__ wsb) {
    int t = blockIdx.x * blockDim.x + threadIdx.x;   // t = k*160 + n (coalesced read)
    if (t >= FD * FD) return;
    int k = t / FD, n = t - k * FD;
    int nt = n >> 4, l15 = n & 15;
    int ks = k >> 5, quad = (k >> 3) & 3, j = k & 7;
    int L = quad * 16 + l15;
    int dst = ((nt * NKS + ks) * 64 + L) * 8 + j;
    wsb[dst] = bf16b(Wd1[t]);
}

__global__ __launch_bounds__(BLOCK)
void prop_mfma(const float* __restrict__ xn,
               const float* __restrict__ xe_attr,
               const float* __restrict__ W1,
               const float* __restrict__ b1,
               const unsigned short* __restrict__ wsb,  // packed bf16 Wd1 B-frags
               const int*   __restrict__ esrc,
               const int*   __restrict__ edst,
               float* __restrict__ out,
               int E)
{
    __shared__ __align__(16) unsigned short sA[TILE_E * ASTR]; // 10752 B bf16 A-matrix [e][k]
    __shared__ __align__(16) float s_attr[TILE_E * ATTRD];     // 4224 B
    __shared__ __align__(16) float s_w1[ATTRD * D];            // 4224 B
    __shared__ __align__(16) float sW[TILE_E * D];             // 4096 B silu(fc1)
    __shared__ float s_b1[D];
    __shared__ float red_s[TILE_E * 2], red_q[TILE_E * 2];
    __shared__ float s_mean[TILE_E], s_scale[TILE_E];
    __shared__ int   s_src[TILE_E], s_dst[TILE_E];
    // total ~24.5 KB

    const int tid   = threadIdx.x;
    const int lane  = tid & 63;
    const int w     = tid >> 6;
    const int mtile = w >> 1;       // 0,1 : edge rows 16*mtile..+16
    const int par   = w & 1;        // N-tile parity: tiles par, par+2, ..., par+8 (== chunk 0..4)
    const int l15   = lane & 15;
    const int quad  = lane >> 4;
    const long e0   = (long)blockIdx.x * TILE_E;
    const int nvalid = min(TILE_E, (int)((long)E - e0));

    // ---------- stage attr tile, W1, b1, indices ----------
    for (int f = tid; f < TILE_E * ATTRD; f += BLOCK) {
        int e = f / ATTRD;
        s_attr[f] = (e < nvalid) ? xe_attr[e0 * ATTRD + f] : 0.0f;
    }
    for (int f = tid; f < ATTRD * D; f += BLOCK) s_w1[f] = W1[f];
    if (tid < D) s_b1[tid] = b1[tid];
    if (tid < TILE_E) {
        s_src[tid] = (tid < nvalid) ? esrc[e0 + tid] : 0;
        s_dst[tid] = (tid < nvalid) ? edst[e0 + tid] : 0;
    }
    __syncthreads();

    // ---------- fc1: W = silu(attr @ W1 + b1), thread = (edge, 4 cols) ----------
    {
        int e  = tid >> 3;
        int j4 = (tid & 7) * 4;
        float a0 = s_b1[j4], a1 = s_b1[j4 + 1], a2 = s_b1[j4 + 2], a3 = s_b1[j4 + 3];
        #pragma unroll
        for (int a = 0; a < ATTRD; ++a) {
            float va = s_attr[e * ATTRD + a];
            float4 w4 = *reinterpret_cast<const float4*>(&s_w1[a * D + j4]);
            a0 = fmaf(va, w4.x, a0); a1 = fmaf(va, w4.y, a1);
            a2 = fmaf(va, w4.z, a2); a3 = fmaf(va, w4.w, a3);
        }
        float4 r;
        r.x = a0 * __builtin_amdgcn_rcpf(1.0f + __expf(-a0));
        r.y = a1 * __builtin_amdgcn_rcpf(1.0f + __expf(-a1));
        r.z = a2 * __builtin_amdgcn_rcpf(1.0f + __expf(-a2));
        r.w = a3 * __builtin_amdgcn_rcpf(1.0f + __expf(-a3));
        *reinterpret_cast<float4*>(&sW[e * D + j4]) = r;
    }
    __syncthreads();

    // ---------- gathers + dxe features + tanh -> sA bf16 [e][k] ----------
    #pragma unroll
    for (int it = 0; it < 2; ++it) {
        int item = tid + BLOCK * it;          // 512 items: (e, col-pair)
        int e = item >> 4, c = (item & 15) * 2;
        int rs = s_src[e], rd = s_dst[e];
        float2 vs = *reinterpret_cast<const float2*>(xn + (size_t)rs * D + c);
        float2 vd = *reinterpret_cast<const float2*>(xn + (size_t)rd * D + c);
        float2 wv = *reinterpret_cast<const float2*>(&sW[e * D + c]);
        float g0 = wv.x * (vs.x - vd.x), A0 = wv.x * (vs.x + vd.x) * 0.5f;
        float g1 = wv.y * (vs.y - vd.y), A1 = wv.y * (vs.y + vd.y) * 0.5f;
        float f0[5] = {g0, A0, g0 * A0, g0 * g0, A0 * A0};
        float f1[5] = {g1, A1, g1 * A1, g1 * g1, A1 * A1};
        #pragma unroll
        for (int q = 0; q < 5; ++q) {
            ushort2 u;
            u.x = bf16b(fast_tanh(f0[q]));
            u.y = bf16b(fast_tanh(f1[q]));
            *reinterpret_cast<ushort2*>(&sA[e * ASTR + q * D + c]) = u;
        }
    }
    __syncthreads();

    const short8* Bp = reinterpret_cast<const short8*>(wsb);
    f32x4 C[5];

    auto run_mm = [&]() {
        #pragma unroll
        for (int t = 0; t < 5; ++t) C[t] = (f32x4){0.f, 0.f, 0.f, 0.f};
        #pragma unroll
        for (int ks = 0; ks < NKS; ++ks) {
            short8 af = *reinterpret_cast<const short8*>(
                &sA[(mtile * 16 + l15) * ASTR + ks * 32 + quad * 8]);
            #pragma unroll
            for (int t = 0; t < 5; ++t) {
                int nt = par + 2 * t;
                short8 bf = Bp[(nt * NKS + ks) * 64 + lane];
                C[t] = __builtin_amdgcn_mfma_f32_16x16x32_bf16(af, bf, C[t], 0, 0, 0);
            }
        }
    };

    // ---------- matmul 1 ----------
    run_mm();

    // ---------- tv_norm stats: row sums over this wave's 80 cols, then combine ----------
    #pragma unroll
    for (int r = 0; r < 4; ++r) {
        float s = C[0][r] + C[1][r] + C[2][r] + C[3][r] + C[4][r];
        float q = C[0][r]*C[0][r] + C[1][r]*C[1][r] + C[2][r]*C[2][r]
                + C[3][r]*C[3][r] + C[4][r]*C[4][r];
        #pragma unroll
        for (int m = 1; m < 16; m <<= 1) {
            s += __shfl_xor(s, m);
            q += __shfl_xor(q, m);
        }
        if (l15 == 0) {
            int row = mtile * 16 + quad * 4 + r;
            red_s[row * 2 + par] = s;
            red_q[row * 2 + par] = q;
        }
    }
    __syncthreads();
    if (tid < TILE_E) {
        float s = red_s[tid * 2] + red_s[tid * 2 + 1];
        float q = red_q[tid * 2] + red_q[tid * 2 + 1];
        float mean = s * (1.0f / FD);
        float var  = q - (float)FD * mean * mean;
        s_mean[tid]  = mean;
        s_scale[tid] = __builtin_amdgcn_rsqf(var + 1e-3f);
    }
    __syncthreads();

    // ---------- tanh(tv_norm(x)) -> sA bf16 for matmul 2 ----------
    #pragma unroll
    for (int t = 0; t < 5; ++t) {
        int j = (par + 2 * t) * 16 + l15;
        #pragma unroll
        for (int r = 0; r < 4; ++r) {
            int row = mtile * 16 + quad * 4 + r;
            float v = (C[t][r] - s_mean[row]) * s_scale[row];
            sA[row * ASTR + j] = bf16b(fast_tanh(v));
        }
    }
    __syncthreads();

    // ---------- matmul 2 ----------
    run_mm();

    // ---------- epilogue: msg = tile(W,5)*tanh(x2); chunk-reduce in-register; atomics ----------
    {
        int c = par * 16 + l15;   // = j & 31 for every tile t of this wave
        #pragma unroll
        for (int r = 0; r < 4; ++r) {
            int e = mtile * 16 + quad * 4 + r;
            if (e >= nvalid) continue;
            float wv = sW[e * D + c];
            float m0 = fast_tanh(C[0][r]) * wv;
            float m1 = fast_tanh(C[1][r]) * wv;
            float m2 = fast_tanh(C[2][r]) * wv;
            float m3 = fast_tanh(C[3][r]) * wv;
            float m4 = fast_tanh(C[4][r]) * wv;
            float A4 = m1 + m2 + m3 + m4;
            atomicAdd(out + (size_t)s_dst[e] * D + c, m0 + 0.5f * A4);
            atomicAdd(out + (size_t)s_src[e] * D + c, 0.5f * A4 - m0);
        }
    }
}

extern "C" void kernel_launch(void* const* d_in, const int* in_sizes, int n_in,
                              void* d_out, int out_size, void* d_ws, size_t ws_size,
                              hipStream_t stream)
{
    const float* xn   = (const float*)d_in[0];
    const float* attr = (const float*)d_in[1];
    const float* W1   = (const float*)d_in[2];
    const float* b1   = (const float*)d_in[3];
    const float* Wd1  = (const float*)d_in[4];
    const int*   esrc = (const int*)d_in[5];
    const int*   edst = (const int*)d_in[6];
    float* out = (float*)d_out;
    unsigned short* wsb = (unsigned short*)d_ws;   // 160*160 bf16 = 51.2 KB packed B-frags
    const int E = in_sizes[5];

    hipMemsetAsync(d_out, 0, (size_t)out_size * sizeof(float), stream);
    prep_wd1<<<(FD * FD + 255) / 256, 256, 0, stream>>>(Wd1, wsb);
    const int grid = (E + TILE_E - 1) / TILE_E;
    prop_mfma<<<grid, BLOCK, 0, stream>>>(xn, attr, W1, b1, wsb, esrc, edst, out, E);
}